// Round 2
// baseline (15590.065 us; speedup 1.0000x reference)
//
#include <hip/hip_runtime.h>

// SNN forward, fp64-accurate trajectory:
// cur = inp @ W^T + b ; m = 0.9*m + cur - (m_prev>1) ; s = (m>1)
// Accumulate in double; membrane state carried across timesteps in fp64 (d_ws)
// so spike/reset decisions match an exact reference bit-for-bit in practice.

#define TM 32
#define TN 64
#define KB 32
#define LDSA (TM + 2)   // float2-aligned rows
#define LDSB (TN + 4)   // float4-aligned rows

__global__ __launch_bounds__(256)
void snn_layer(const float* __restrict__ A,         // M x K activations (fp32)
               const float* __restrict__ W,         // N x K weights (fp32)
               const float* __restrict__ bias,      // N
               const double* __restrict__ mem_prev, // M x N fp64 state, or nullptr
               double* __restrict__ mem_ws,         // M x N fp64 state out
               float* __restrict__ spk_out,         // M x N
               float* __restrict__ mem_out,         // M x N
               int M, int N, int K)
{
    __shared__ float As[KB][LDSA];   // k-major: As[k][m]
    __shared__ float Bs[KB][LDSB];   // k-major: Bs[k][n]

    const int tid = threadIdx.x;
    const int tx  = tid & 15;        // col group: 4 cols each
    const int ty  = tid >> 4;        // row group: 2 rows each
    const int bm  = blockIdx.y * TM;
    const int bn  = blockIdx.x * TN;

    const int lr = tid >> 3;         // loader row 0..31
    const int lk = (tid & 7) * 4;    // loader k offset 0,4,...,28

    double c[2][4];
#pragma unroll
    for (int i = 0; i < 2; ++i)
#pragma unroll
        for (int j = 0; j < 4; ++j) c[i][j] = 0.0;

    for (int kb = 0; kb < K; kb += KB) {
        // stage A tile (32 rows x 32 k), transpose to k-major
        {
            int gr = bm + lr;
            float4 v = make_float4(0.f, 0.f, 0.f, 0.f);
            if (gr < M && (kb + lk) < K)       // K%4==0: all-or-nothing per float4
                v = *reinterpret_cast<const float4*>(&A[(size_t)gr * K + kb + lk]);
            As[lk + 0][lr] = v.x;
            As[lk + 1][lr] = v.y;
            As[lk + 2][lr] = v.z;
            As[lk + 3][lr] = v.w;
        }
        // stage W tile (64 rows x 32 k), transpose to k-major
#pragma unroll
        for (int h = 0; h < 2; ++h) {
            int row = lr + h * 32;
            int gn  = bn + row;
            float4 v = make_float4(0.f, 0.f, 0.f, 0.f);
            if (gn < N && (kb + lk) < K)
                v = *reinterpret_cast<const float4*>(&W[(size_t)gn * K + kb + lk]);
            Bs[lk + 0][row] = v.x;
            Bs[lk + 1][row] = v.y;
            Bs[lk + 2][row] = v.z;
            Bs[lk + 3][row] = v.w;
        }
        __syncthreads();

#pragma unroll
        for (int k = 0; k < KB; ++k) {
            float2 a2 = *reinterpret_cast<const float2*>(&As[k][ty * 2]);
            float4 b4 = *reinterpret_cast<const float4*>(&Bs[k][tx * 4]);
            double a[2] = {(double)a2.x, (double)a2.y};
            double b[4] = {(double)b4.x, (double)b4.y, (double)b4.z, (double)b4.w};
#pragma unroll
            for (int i = 0; i < 2; ++i)
#pragma unroll
                for (int j = 0; j < 4; ++j)
                    c[i][j] += a[i] * b[j];
        }
        __syncthreads();
    }

    // epilogue: bias + leaky-IF update in fp64
#pragma unroll
    for (int i = 0; i < 2; ++i) {
        int row = bm + ty * 2 + i;
        if (row >= M) continue;
#pragma unroll
        for (int j = 0; j < 4; ++j) {
            int col = bn + tx * 4 + j;
            if (col >= N) continue;
            size_t idx = (size_t)row * N + col;
            double cur = c[i][j] + (double)bias[col];
            double mp  = mem_prev ? mem_prev[idx] : 0.0;
            double reset = (mp > 1.0) ? 1.0 : 0.0;
            double mn = 0.9 * mp + cur - reset;   // (beta*m + cur) - reset*TH
            spk_out[idx] = (mn > 1.0) ? 1.0f : 0.0f;
            mem_out[idx] = (float)mn;
            mem_ws[idx]  = mn;
        }
    }
}

extern "C" void kernel_launch(void* const* d_in, const int* in_sizes, int n_in,
                              void* d_out, int out_size, void* d_ws, size_t ws_size,
                              hipStream_t stream)
{
    const float* x  = (const float*)d_in[0];
    const float* W0 = (const float*)d_in[1];
    const float* b0 = (const float*)d_in[2];
    const float* W1 = (const float*)d_in[3];
    const float* b1 = (const float*)d_in[4];
    const float* W2 = (const float*)d_in[5];
    const float* b2 = (const float*)d_in[6];
    const float* W3 = (const float*)d_in[7];
    const float* b3 = (const float*)d_in[8];
    float* out = (float*)d_out;

    const int T = 50, B = 512, NIN = 784, NH = 1000, NOUT = 10;
    const size_t LNH = (size_t)B * NH;    // 512000
    const size_t LNO = (size_t)B * NOUT;  // 5120

    float* spk0 = out;
    float* spk1 = spk0 + (size_t)T * LNH;
    float* spk2 = spk1 + (size_t)T * LNH;
    float* spk3 = spk2 + (size_t)T * LNH;
    float* mem0 = spk3 + (size_t)T * LNO;
    float* mem1 = mem0 + (size_t)T * LNH;
    float* mem2 = mem1 + (size_t)T * LNH;
    float* mem3 = mem2 + (size_t)T * LNH;

    // fp64 membrane state in workspace: 3*512000 + 5120 doubles = 12.3 MB
    double* mw0 = (double*)d_ws;
    double* mw1 = mw0 + LNH;
    double* mw2 = mw1 + LNH;
    double* mw3 = mw2 + LNH;

    dim3 blk(256);
    dim3 gridH((NH + TN - 1) / TN, B / TM);    // 16 x 16 = 256 blocks
    dim3 gridO((NOUT + TN - 1) / TN, B / TM);  // 1 x 16

    for (int t = 0; t < T; ++t) {
        const float* xt = x + (size_t)t * B * NIN;

        snn_layer<<<gridH, blk, 0, stream>>>(
            xt, W0, b0, t ? mw0 : nullptr, mw0,
            spk0 + (size_t)t * LNH, mem0 + (size_t)t * LNH, B, NH, NIN);

        snn_layer<<<gridH, blk, 0, stream>>>(
            spk0 + (size_t)t * LNH, W1, b1, t ? mw1 : nullptr, mw1,
            spk1 + (size_t)t * LNH, mem1 + (size_t)t * LNH, B, NH, NH);

        snn_layer<<<gridH, blk, 0, stream>>>(
            spk1 + (size_t)t * LNH, W2, b2, t ? mw2 : nullptr, mw2,
            spk2 + (size_t)t * LNH, mem2 + (size_t)t * LNH, B, NH, NH);

        snn_layer<<<gridO, blk, 0, stream>>>(
            spk2 + (size_t)t * LNH, W3, b3, t ? mw3 : nullptr, mw3,
            spk3 + (size_t)t * LNO, mem3 + (size_t)t * LNO, B, NOUT, NH);
    }
}

// Round 4
// 5200.825 us; speedup vs baseline: 2.9976x; 2.9976x over previous
//
#include <hip/hip_runtime.h>

// SNN forward via EXACT fixed-point int8 MFMA.
// Reference trajectory is fp64; spike decisions (m>1) have gaps ~1e-8, so the
// GEMM must be accurate to ~3e-10. Scheme:
//  - layers 1-3: A = spikes (exact {0,1} int8), W = 5 balanced base-256 int8
//    digits of round(w*2^40). Sum is exact integer math in i32 MFMA accums,
//    reconstructed in fp64 (< 2^53, exact). Only error: W quantization ~1e-11.
//  - layer 0: x digitized to round(x*2^36) (5 digits, on the fly in staging),
//    digit pairs p+q>=4 kept (error ~4e-11), bucketed by scale into 5 accums.
//  - membrane recurrence carried in fp64 in d_ws.

typedef int int4v __attribute__((ext_vector_type(4)));

#define XSCALE 68719476736.0      // 2^36
#define WSCALE 1099511627776.0    // 2^40

// fp32 [N][K] -> 5 balanced int8 digit planes [N][Kpad] of round(w*2^40)
__global__ void wsplit_i8(const float* __restrict__ W, signed char* __restrict__ out,
                          int N, int K, int Kpad)
{
    int idx = blockIdx.x * blockDim.x + threadIdx.x;
    int total = N * Kpad;
    if (idx >= total) return;
    int n = idx / Kpad, k = idx - n * Kpad;
    long long v = 0;
    if (k < K) v = __double2ll_rn((double)W[(size_t)n * K + k] * WSCALE);
    size_t plane = (size_t)total;
#pragma unroll
    for (int p = 0; p < 4; ++p) {
        int d = (int)(v & 255); if (d > 127) d -= 256;
        out[p * plane + idx] = (signed char)d;
        v = (v - d) >> 8;
    }
    out[4 * plane + idx] = (signed char)v;   // |v| <= 127 by range bound
}

// Fused exact-int GEMM + fp64 leaky-IF epilogue.
// Block 256 thr = 4 waves; block tile 32(M) x 64(N); wave tile 16 x 32 (2 MFMA tiles).
template<bool L0>
__global__ __launch_bounds__(256)
void snn_i8(const float* __restrict__ Afp,        // L0: x_t [512][K] fp32
            const signed char* __restrict__ Asp,  // else: spike plane [512][1024]
            const signed char* __restrict__ Wd,   // 5 planes [N][Kpad]
            const float* __restrict__ bias,
            const double* __restrict__ mem_prev,  // [512][N] fp64 or null (t=0)
            double* __restrict__ mem_ws,          // [512][N] fp64 out
            float* __restrict__ spk, float* __restrict__ mem,
            signed char* __restrict__ spk_i8,     // [512][1024] or null
            int N, int K, int Kpad)
{
    constexpr int NA = L0 ? 5 : 1;
    __shared__ __align__(16) signed char Ald[NA * 32 * 80];
    __shared__ __align__(16) signed char Wld[5 * 64 * 80];

    const int tid = threadIdx.x;
    const int l  = tid & 63;
    const int w  = tid >> 6;
    const int wm = (w >> 1) * 16;       // 0/16
    const int wn = (w & 1) * 32;        // 0/32
    const int bm = blockIdx.y * 32;
    const int bn = blockIdx.x * 64;
    const int fr = l & 15;
    const int g  = l >> 4;              // 0..3 -> 16B chunk of the 64B row
    const size_t planeW = (size_t)N * Kpad;

    int4v acc[2][5];
#pragma unroll
    for (int t2 = 0; t2 < 2; ++t2)
#pragma unroll
        for (int s = 0; s < 5; ++s) acc[t2][s] = (int4v){0, 0, 0, 0};

    for (int kb = 0; kb < Kpad; kb += 64) {
        __syncthreads();
        // ---- stage W: 5 planes x 64 rows x 64B ----
        {
            int row = tid >> 2, c16 = (tid & 3) * 16;
            int gn = bn + row;
#pragma unroll
            for (int p = 0; p < 5; ++p) {
                int4v v = (int4v){0, 0, 0, 0};
                if (gn < N)
                    v = *(const int4v*)&Wd[p * planeW + (size_t)gn * Kpad + kb + c16];
                *(int4v*)&Wld[(p * 64 + row) * 80 + c16] = v;
            }
        }
        // ---- stage A ----
        if constexpr (L0) {
            // digitize x on the fly: 8 floats/thread -> 5 digit planes
            int row = tid >> 3, k0 = (tid & 7) * 8;
            size_t base = (size_t)(bm + row) * K + kb + k0;
            float xv[8];
            if (kb + k0 + 8 <= K) {
                float4 a4 = *(const float4*)&Afp[base];
                float4 b4 = *(const float4*)&Afp[base + 4];
                xv[0]=a4.x; xv[1]=a4.y; xv[2]=a4.z; xv[3]=a4.w;
                xv[4]=b4.x; xv[5]=b4.y; xv[6]=b4.z; xv[7]=b4.w;
            } else {
#pragma unroll
                for (int j = 0; j < 8; ++j) {
                    int gk = kb + k0 + j;
                    xv[j] = (gk < K) ? Afp[base + j] : 0.f;
                }
            }
            unsigned pk[5][2] = {{0,0},{0,0},{0,0},{0,0},{0,0}};
#pragma unroll
            for (int j = 0; j < 8; ++j) {
                long long v = __double2ll_rn((double)xv[j] * XSCALE);
#pragma unroll
                for (int p = 0; p < 4; ++p) {
                    int d = (int)(v & 255); if (d > 127) d -= 256;
                    pk[p][j >> 2] |= (unsigned)(d & 255) << ((j & 3) * 8);
                    v = (v - d) >> 8;
                }
                pk[4][j >> 2] |= (unsigned)((int)v & 255) << ((j & 3) * 8);
            }
#pragma unroll
            for (int p = 0; p < 5; ++p) {
                unsigned long long u = (unsigned long long)pk[p][0]
                                     | ((unsigned long long)pk[p][1] << 32);
                *(unsigned long long*)&Ald[(p * 32 + row) * 80 + k0] = u;
            }
        } else {
            int row = tid >> 3, c8 = (tid & 7) * 8;
            unsigned long long v =
                *(const unsigned long long*)&Asp[(size_t)(bm + row) * 1024 + kb + c8];
            *(unsigned long long*)&Ald[row * 80 + c8] = v;
        }
        __syncthreads();

        // ---- fragments: row/col = l&15, k-chunk = 16B at 16*(l>>4).
        // Any HW k-permutation cancels (A and B use identical maps). ----
        int4v af[NA], bf[2][5];
#pragma unroll
        for (int p = 0; p < NA; ++p)
            af[p] = *(const int4v*)&Ald[(p * 32 + wm + fr) * 80 + 16 * g];
#pragma unroll
        for (int t2 = 0; t2 < 2; ++t2)
#pragma unroll
            for (int p = 0; p < 5; ++p)
                bf[t2][p] = *(const int4v*)&Wld[(p * 64 + wn + t2 * 16 + fr) * 80 + 16 * g];

#pragma unroll
        for (int t2 = 0; t2 < 2; ++t2) {
            if constexpr (L0) {
#pragma unroll
                for (int q = 0; q < 5; ++q)
#pragma unroll
                    for (int p = 0; p < 5; ++p)
                        if (p + q >= 4)
                            acc[t2][p + q - 4] = __builtin_amdgcn_mfma_i32_16x16x64_i8(
                                af[p], bf[t2][q], acc[t2][p + q - 4], 0, 0, 0);
            } else {
#pragma unroll
                for (int q = 0; q < 5; ++q)
                    acc[t2][q] = __builtin_amdgcn_mfma_i32_16x16x64_i8(
                        af[0], bf[t2][q], acc[t2][q], 0, 0, 0);
            }
        }
    }

    // ---- epilogue: fp64 reconstruction + leaky-IF ----
    // C/D layout (m89-verified, dtype-independent): col=l&15, row=4*(l>>4)+reg.
#pragma unroll
    for (int t2 = 0; t2 < 2; ++t2) {
        int col = bn + wn + t2 * 16 + fr;
        if (col >= N) continue;
        double bs = (double)bias[col];
#pragma unroll
        for (int r = 0; r < 4; ++r) {
            int row = bm + wm + 4 * g + r;
            size_t idx = (size_t)row * N + col;
            double v = (double)acc[t2][4][r];
            v = v * 256.0 + (double)acc[t2][3][r];
            v = v * 256.0 + (double)acc[t2][2][r];
            v = v * 256.0 + (double)acc[t2][1][r];
            v = v * 256.0 + (double)acc[t2][0][r];
            double cur = v * (L0 ? 0x1p-44 : 0x1p-40) + bs;
            double mp  = mem_prev ? mem_prev[idx] : 0.0;
            double rst = (mp > 1.0) ? 1.0 : 0.0;
            double mn  = 0.9 * mp + cur - rst;
            spk[idx] = (mn > 1.0) ? 1.0f : 0.0f;
            mem[idx] = (float)mn;
            mem_ws[idx] = mn;
            if (spk_i8)
                spk_i8[(size_t)row * 1024 + col] = (signed char)((mn > 1.0) ? 1 : 0);
        }
    }
}

extern "C" void kernel_launch(void* const* d_in, const int* in_sizes, int n_in,
                              void* d_out, int out_size, void* d_ws, size_t ws_size,
                              hipStream_t stream)
{
    const float* x  = (const float*)d_in[0];
    const float* W0 = (const float*)d_in[1];
    const float* b0 = (const float*)d_in[2];
    const float* W1 = (const float*)d_in[3];
    const float* b1 = (const float*)d_in[4];
    const float* W2 = (const float*)d_in[5];
    const float* b2 = (const float*)d_in[6];
    const float* W3 = (const float*)d_in[7];
    const float* b3 = (const float*)d_in[8];
    float* out = (float*)d_out;

    const int T = 50, NIN = 784, NH = 1000, NOUT = 10;
    const int K0P = 832, KHP = 1024;   // Kpad multiples of 64
    const size_t LNH = (size_t)512 * NH;
    const size_t LNO = (size_t)512 * NOUT;

    float* spk0 = out;
    float* spk1 = spk0 + (size_t)T * LNH;
    float* spk2 = spk1 + (size_t)T * LNH;
    float* spk3 = spk2 + (size_t)T * LNH;
    float* mem0 = spk3 + (size_t)T * LNO;
    float* mem1 = mem0 + (size_t)T * LNH;
    float* mem2 = mem1 + (size_t)T * LNH;
    float* mem3 = mem2 + (size_t)T * LNH;

    // ---- workspace layout ----
    signed char* W0d = (signed char*)d_ws;                    // 5*1000*832  = 4.16 MB
    signed char* W1d = W0d + (size_t)5 * 1000 * K0P;          // 5*1000*1024 = 5.12 MB
    signed char* W2d = W1d + (size_t)5 * 1000 * KHP;
    signed char* W3d = W2d + (size_t)5 * 1000 * KHP;          // 5*10*1024
    signed char* s0b = W3d + (size_t)5 * 10 * KHP;            // 512*1024 each
    signed char* s1b = s0b + (size_t)512 * KHP;
    signed char* s2b = s1b + (size_t)512 * KHP;
    double* mw0 = (double*)(s2b + (size_t)512 * KHP);         // fp64 mem state
    double* mw1 = mw0 + LNH;
    double* mw2 = mw1 + LNH;
    double* mw3 = mw2 + LNH;

    // zero spike buffers once (K-tails 1000..1023 must be 0 for the next GEMM)
    hipMemsetAsync(s0b, 0, (size_t)3 * 512 * KHP, stream);

    // W digit splits (once per call, parallel)
    {
        int t0 = 1000 * K0P, th = 1000 * KHP, t3 = 10 * KHP;
        wsplit_i8<<<(t0 + 255) / 256, 256, 0, stream>>>(W0, W0d, 1000, NIN, K0P);
        wsplit_i8<<<(th + 255) / 256, 256, 0, stream>>>(W1, W1d, 1000, NH, KHP);
        wsplit_i8<<<(th + 255) / 256, 256, 0, stream>>>(W2, W2d, 1000, NH, KHP);
        wsplit_i8<<<(t3 + 255) / 256, 256, 0, stream>>>(W3, W3d, 10, NH, KHP);
    }

    dim3 blk(256);
    dim3 gridH(16, 16);   // cols: 16*64 >= 1000 ; rows: 16*32 = 512
    dim3 gridO(1, 16);

    for (int t = 0; t < T; ++t) {
        const float* xt = x + (size_t)t * 512 * NIN;

        snn_i8<true><<<gridH, blk, 0, stream>>>(
            xt, nullptr, W0d, b0, t ? mw0 : nullptr, mw0,
            spk0 + (size_t)t * LNH, mem0 + (size_t)t * LNH, s0b, NH, NIN, K0P);

        snn_i8<false><<<gridH, blk, 0, stream>>>(
            nullptr, s0b, W1d, b1, t ? mw1 : nullptr, mw1,
            spk1 + (size_t)t * LNH, mem1 + (size_t)t * LNH, s1b, NH, NH, KHP);

        snn_i8<false><<<gridH, blk, 0, stream>>>(
            nullptr, s1b, W2d, b2, t ? mw2 : nullptr, mw2,
            spk2 + (size_t)t * LNH, mem2 + (size_t)t * LNH, s2b, NH, NH, KHP);

        snn_i8<false><<<gridO, blk, 0, stream>>>(
            nullptr, s2b, W3d, b3, t ? mw3 : nullptr, mw3,
            spk3 + (size_t)t * LNO, mem3 + (size_t)t * LNO, nullptr, NOUT, NH, KHP);
    }
}

// Round 5
// 2800.371 us; speedup vs baseline: 5.5671x; 1.8572x over previous
//
#include <hip/hip_runtime.h>

// SNN forward via EXACT fixed-point int8 MFMA, diagonal-wavefront batched.
// Layers (L0,t),(L1,t-1),(L2,t-2),(L3,t-3) are independent -> one kernel per
// diagonal d=0..52 instead of 4 dependent launches per timestep.
// Numerics identical to round 4 (passed): spikes exact in i8; W = 5 balanced
// base-256 digits of round(w*2^40); layer-0 x digitized to round(x*2^36) in
// staging; i32 MFMA accumulation is exact; fp64 reconstruction (<2^53 exact);
// membrane recurrence carried in fp64 (d_ws). Spike i8 buffers double-buffered
// by t-parity so a diagonal's writers/readers never touch the same buffer.

typedef int int4v __attribute__((ext_vector_type(4)));

#define XSCALE 68719476736.0      // 2^36
#define WSCALE 1099511627776.0    // 2^40

struct DiagParams {
    const float* x;
    const signed char* Wd[4];
    const float* bias[4];
    double* mw[4];
    float* spk[4];
    float* mem[4];
    signed char* sb[3][2];        // spike i8 buffers [layer][t&1], 512x1024
};

// fp32 [N][K] -> 5 balanced int8 digit planes [N][Kpad] of round(w*2^40)
__global__ void wsplit_i8(const float* __restrict__ W, signed char* __restrict__ out,
                          int N, int K, int Kpad)
{
    int idx = blockIdx.x * blockDim.x + threadIdx.x;
    int total = N * Kpad;
    if (idx >= total) return;
    int n = idx / Kpad, k = idx - n * Kpad;
    long long v = 0;
    if (k < K) v = __double2ll_rn((double)W[(size_t)n * K + k] * WSCALE);
    size_t plane = (size_t)total;
#pragma unroll
    for (int p = 0; p < 4; ++p) {
        int d = (int)(v & 255); if (d > 127) d -= 256;
        out[p * plane + idx] = (signed char)d;
        v = (v - d) >> 8;
    }
    out[4 * plane + idx] = (signed char)v;
}

// One (layer, m-tile, n-tile) task: exact-int GEMM tile + fp64 leaky-IF epilogue.
// Block 512 thr = 8 waves; block tile 64(M) x 64(N); wave tile 16 x 32.
template<bool L0>
__device__ __forceinline__ void run_layer(
    const float* __restrict__ Afp,       // L0: x_t [512][K] fp32
    const signed char* __restrict__ Asp, // else: spike plane [512][1024]
    const signed char* __restrict__ Wd,  // 5 planes [N][Kpad]
    const float* __restrict__ bias,
    double* __restrict__ mw,             // [512][N] fp64 state (read t-1, write t)
    float* __restrict__ spk, float* __restrict__ mem,
    signed char* __restrict__ spk_i8,    // [512][1024] or null
    int N, int K, int Kpad, int bm, int bn, bool has_prev,
    signed char* Ald, signed char* Wld)
{
    constexpr int NA = L0 ? 5 : 1;
    const int tid = threadIdx.x;
    const int l   = tid & 63;
    const int w   = tid >> 6;          // 0..7
    const int wm  = (w & 3) * 16;      // 0,16,32,48
    const int wn  = (w >> 2) * 32;     // 0,32
    const int fr  = l & 15;
    const int g   = l >> 4;            // 16B chunk select
    const size_t planeW = (size_t)N * Kpad;

    const int srow = tid >> 3;         // 0..63
    const int c8   = (tid & 7) * 8;    // 0..56

    int4v acc[2][5];
#pragma unroll
    for (int t2 = 0; t2 < 2; ++t2)
#pragma unroll
        for (int s = 0; s < 5; ++s) acc[t2][s] = (int4v){0, 0, 0, 0};

    for (int kb = 0; kb < Kpad; kb += 64) {
        __syncthreads();
        // ---- stage W: 5 planes x 64 rows x 64B (b64 per thread per plane) ----
        {
            int gn = bn + srow;
#pragma unroll
            for (int p = 0; p < 5; ++p) {
                unsigned long long v = 0;
                if (gn < N)
                    v = *(const unsigned long long*)&Wd[p * planeW + (size_t)gn * Kpad + kb + c8];
                *(unsigned long long*)&Wld[(p * 64 + srow) * 80 + c8] = v;
            }
        }
        // ---- stage A ----
        if constexpr (L0) {
            float xv[8];
            size_t base = (size_t)(bm + srow) * K + kb + c8;
            if (kb + c8 + 8 <= K) {
                float4 a4 = *(const float4*)&Afp[base];
                float4 b4 = *(const float4*)&Afp[base + 4];
                xv[0]=a4.x; xv[1]=a4.y; xv[2]=a4.z; xv[3]=a4.w;
                xv[4]=b4.x; xv[5]=b4.y; xv[6]=b4.z; xv[7]=b4.w;
            } else {
#pragma unroll
                for (int j = 0; j < 8; ++j) {
                    int gk = kb + c8 + j;
                    xv[j] = (gk < K) ? Afp[base + j] : 0.f;
                }
            }
            unsigned pk[5][2] = {{0,0},{0,0},{0,0},{0,0},{0,0}};
#pragma unroll
            for (int j = 0; j < 8; ++j) {
                long long v = __double2ll_rn((double)xv[j] * XSCALE);
#pragma unroll
                for (int p = 0; p < 4; ++p) {
                    int dg = (int)(v & 255); if (dg > 127) dg -= 256;
                    pk[p][j >> 2] |= (unsigned)(dg & 255) << ((j & 3) * 8);
                    v = (v - dg) >> 8;
                }
                pk[4][j >> 2] |= (unsigned)((int)v & 255) << ((j & 3) * 8);
            }
#pragma unroll
            for (int p = 0; p < 5; ++p) {
                unsigned long long u = (unsigned long long)pk[p][0]
                                     | ((unsigned long long)pk[p][1] << 32);
                *(unsigned long long*)&Ald[(p * 64 + srow) * 80 + c8] = u;
            }
        } else {
            unsigned long long v =
                *(const unsigned long long*)&Asp[(size_t)(bm + srow) * 1024 + kb + c8];
            *(unsigned long long*)&Ald[srow * 80 + c8] = v;
        }
        __syncthreads();

        // ---- fragments (k-permutation cancels: A,B use identical maps) ----
        int4v af[NA], bf[2][5];
#pragma unroll
        for (int p = 0; p < NA; ++p)
            af[p] = *(const int4v*)&Ald[(p * 64 + wm + fr) * 80 + 16 * g];
#pragma unroll
        for (int t2 = 0; t2 < 2; ++t2)
#pragma unroll
            for (int q = 0; q < 5; ++q)
                bf[t2][q] = *(const int4v*)&Wld[(q * 64 + wn + t2 * 16 + fr) * 80 + 16 * g];

#pragma unroll
        for (int t2 = 0; t2 < 2; ++t2) {
            if constexpr (L0) {
#pragma unroll
                for (int q = 0; q < 5; ++q)
#pragma unroll
                    for (int p = 0; p < 5; ++p)
                        if (p + q >= 4)
                            acc[t2][p + q - 4] = __builtin_amdgcn_mfma_i32_16x16x64_i8(
                                af[p], bf[t2][q], acc[t2][p + q - 4], 0, 0, 0);
            } else {
#pragma unroll
                for (int q = 0; q < 5; ++q)
                    acc[t2][q] = __builtin_amdgcn_mfma_i32_16x16x64_i8(
                        af[0], bf[t2][q], acc[t2][q], 0, 0, 0);
            }
        }
    }

    // ---- epilogue: fp64 reconstruction + leaky-IF (C/D: col=l&15, row=4*(l>>4)+r) ----
#pragma unroll
    for (int t2 = 0; t2 < 2; ++t2) {
        int col = bn + wn + t2 * 16 + fr;
        if (col >= N) continue;
        double bs = (double)bias[col];
#pragma unroll
        for (int r = 0; r < 4; ++r) {
            int row = bm + wm + 4 * g + r;
            size_t idx = (size_t)row * N + col;
            double v = (double)acc[t2][4][r];
            v = v * 256.0 + (double)acc[t2][3][r];
            v = v * 256.0 + (double)acc[t2][2][r];
            v = v * 256.0 + (double)acc[t2][1][r];
            v = v * 256.0 + (double)acc[t2][0][r];
            double cur = v * (L0 ? 0x1p-44 : 0x1p-40) + bs;
            double mp  = has_prev ? mw[idx] : 0.0;
            double rst = (mp > 1.0) ? 1.0 : 0.0;
            double mn  = 0.9 * mp + cur - rst;
            spk[idx] = (mn > 1.0) ? 1.0f : 0.0f;
            mem[idx] = (float)mn;
            mw[idx]  = mn;
            if (spk_i8)
                spk_i8[(size_t)row * 1024 + col] = (signed char)((mn > 1.0) ? 1 : 0);
        }
    }
}

// Diagonal d: tasks = L0(t=d): 128 tiles, L1(t=d-1): 128, L2(t=d-2): 128, L3(t=d-3): 8.
__global__ __launch_bounds__(512)
void snn_diag(DiagParams P, int d)
{
    __shared__ __align__(16) signed char Ald[5 * 64 * 80];
    __shared__ __align__(16) signed char Wld[5 * 64 * 80];

    const int bid  = blockIdx.x;
    const int wgid = (bid & 7) * 49 + (bid >> 3);   // 392 = 8*49: bijective XCD remap
    int layer, lid;
    if (wgid < 384) { layer = wgid >> 7; lid = wgid & 127; }
    else            { layer = 3;         lid = wgid - 384; }
    const int t = d - layer;
    if (t < 0 || t >= 50) return;

    const size_t LNH = (size_t)512 * 1000;
    const size_t LNO = (size_t)512 * 10;

    if (layer == 0) {
        int bn = (lid >> 3) * 64, bm = (lid & 7) * 64;
        run_layer<true>(P.x + (size_t)t * 512 * 784, nullptr, P.Wd[0], P.bias[0],
                        P.mw[0], P.spk[0] + t * LNH, P.mem[0] + t * LNH,
                        P.sb[0][t & 1], 1000, 784, 832, bm, bn, t > 0, Ald, Wld);
    } else if (layer == 1) {
        int bn = (lid >> 3) * 64, bm = (lid & 7) * 64;
        run_layer<false>(nullptr, P.sb[0][t & 1], P.Wd[1], P.bias[1],
                         P.mw[1], P.spk[1] + t * LNH, P.mem[1] + t * LNH,
                         P.sb[1][t & 1], 1000, 1000, 1024, bm, bn, t > 0, Ald, Wld);
    } else if (layer == 2) {
        int bn = (lid >> 3) * 64, bm = (lid & 7) * 64;
        run_layer<false>(nullptr, P.sb[1][t & 1], P.Wd[2], P.bias[2],
                         P.mw[2], P.spk[2] + t * LNH, P.mem[2] + t * LNH,
                         P.sb[2][t & 1], 1000, 1000, 1024, bm, bn, t > 0, Ald, Wld);
    } else {
        int bn = 0, bm = lid * 64;
        run_layer<false>(nullptr, P.sb[2][t & 1], P.Wd[3], P.bias[3],
                         P.mw[3], P.spk[3] + t * LNO, P.mem[3] + t * LNO,
                         nullptr, 10, 1000, 1024, bm, bn, t > 0, Ald, Wld);
    }
}

extern "C" void kernel_launch(void* const* d_in, const int* in_sizes, int n_in,
                              void* d_out, int out_size, void* d_ws, size_t ws_size,
                              hipStream_t stream)
{
    const float* x  = (const float*)d_in[0];
    const float* W0 = (const float*)d_in[1];
    const float* b0 = (const float*)d_in[2];
    const float* W1 = (const float*)d_in[3];
    const float* b1 = (const float*)d_in[4];
    const float* W2 = (const float*)d_in[5];
    const float* b2 = (const float*)d_in[6];
    const float* W3 = (const float*)d_in[7];
    const float* b3 = (const float*)d_in[8];
    float* out = (float*)d_out;

    const int T = 50;
    const int K0P = 832, KHP = 1024;
    const size_t LNH = (size_t)512 * 1000;
    const size_t LNO = (size_t)512 * 10;

    float* spk0 = out;
    float* spk1 = spk0 + (size_t)T * LNH;
    float* spk2 = spk1 + (size_t)T * LNH;
    float* spk3 = spk2 + (size_t)T * LNH;
    float* mem0 = spk3 + (size_t)T * LNO;
    float* mem1 = mem0 + (size_t)T * LNH;
    float* mem2 = mem1 + (size_t)T * LNH;
    float* mem3 = mem2 + (size_t)T * LNH;

    // ---- workspace layout ----
    signed char* W0d = (signed char*)d_ws;
    signed char* W1d = W0d + (size_t)5 * 1000 * K0P;
    signed char* W2d = W1d + (size_t)5 * 1000 * KHP;
    signed char* W3d = W2d + (size_t)5 * 1000 * KHP;
    signed char* sbb = W3d + (size_t)5 * 10 * KHP;     // 6 spike buffers, 512KB each
    double* mw0 = (double*)(sbb + (size_t)6 * 512 * KHP);
    double* mw1 = mw0 + LNH;
    double* mw2 = mw1 + LNH;
    double* mw3 = mw2 + LNH;

    // zero spike buffers (K-tail cols 1000..1023 must stay 0)
    hipMemsetAsync(sbb, 0, (size_t)6 * 512 * KHP, stream);

    // W digit splits (once per call)
    {
        int t0 = 1000 * K0P, th = 1000 * KHP, t3 = 10 * KHP;
        wsplit_i8<<<(t0 + 255) / 256, 256, 0, stream>>>(W0, W0d, 1000, 784, K0P);
        wsplit_i8<<<(th + 255) / 256, 256, 0, stream>>>(W1, W1d, 1000, 1000, KHP);
        wsplit_i8<<<(th + 255) / 256, 256, 0, stream>>>(W2, W2d, 1000, 1000, KHP);
        wsplit_i8<<<(t3 + 255) / 256, 256, 0, stream>>>(W3, W3d, 10, 1000, KHP);
    }

    DiagParams P;
    P.x = x;
    P.Wd[0] = W0d; P.Wd[1] = W1d; P.Wd[2] = W2d; P.Wd[3] = W3d;
    P.bias[0] = b0; P.bias[1] = b1; P.bias[2] = b2; P.bias[3] = b3;
    P.mw[0] = mw0; P.mw[1] = mw1; P.mw[2] = mw2; P.mw[3] = mw3;
    P.spk[0] = spk0; P.spk[1] = spk1; P.spk[2] = spk2; P.spk[3] = spk3;
    P.mem[0] = mem0; P.mem[1] = mem1; P.mem[2] = mem2; P.mem[3] = mem3;
    for (int ly = 0; ly < 3; ++ly)
        for (int pp = 0; pp < 2; ++pp)
            P.sb[ly][pp] = sbb + ((size_t)(ly * 2 + pp)) * 512 * KHP;

    for (int d = 0; d < T + 3; ++d)
        snn_diag<<<392, 512, 0, stream>>>(P, d);
}